// Round 10
// baseline (63.581 us; speedup 1.0000x reference)
//
#include <hip/hip_runtime.h>
#include <hip/hip_bf16.h>
#include <stdint.h>

#define NS 8192
#define NHALF 4096
#define DIM 256
#define BLK 128
#define BK 32
#define NKT (DIM / BK)           // 8 K-steps
#define NTILES (NS / BLK)        // 64
#define HALF_TILES (NHALF / BLK) // 32
#define NTRI (NTILES * (NTILES + 1) / 2)  // 2080 upper-tri tiles
#define PREP_BLOCKS 256

typedef __attribute__((ext_vector_type(8))) short bf16x8;
typedef __attribute__((ext_vector_type(4))) float f32x4;
typedef __attribute__((ext_vector_type(8))) unsigned short u16x8;

// workspace layout (bytes) — round-0 proven layout
#define XB_OFF   0                         // bf16 X: 8192*256*2 = 4 MiB
#define SQ_OFF   (NS * DIM * 2)            // f32 sq[8192] = 32 KiB
#define PART_OFF (SQ_OFF + NS * 4)         // f32 partials[256][256] = 256 KiB
#define ACC_OFF  (PART_OFF + PREP_BLOCKS * DIM * 4)  // f64 signed kernel sum
#define C0_OFF   (ACC_OFF + 8)             // f32 log2e / bandwidth
#define WS_NEED  (C0_OFF + 16)

__device__ __forceinline__ unsigned short f2bf(float f) {
  unsigned int u = __float_as_uint(f);
  u += 0x7fffu + ((u >> 16) & 1u);   // round-to-nearest-even
  return (unsigned short)(u >> 16);
}
__device__ __forceinline__ float bf2f(unsigned short h) {
  return __uint_as_float(((unsigned int)h) << 16);
}

// ---- Kernel 1: convert to bf16, row ||x||^2, per-block column partials ----
// (round-0 exact + block 0 zeroes accK, replacing the hipMemsetAsync dispatch)
__global__ __launch_bounds__(256) void mmd_prep(
    const float* __restrict__ src, const float* __restrict__ tgt,
    unsigned short* __restrict__ Xb, float* __restrict__ sq,
    float* __restrict__ partials, double* __restrict__ accK) {
  int tid = threadIdx.x;
  if (blockIdx.x == 0 && tid == 0) accK[0] = 0.0;   // stream-ordered before gram
  int lane32 = tid & 31;
  int rgrp = tid >> 5;
  int c = lane32 * 8;
  int rowBase = blockIdx.x * 32;

  float colpart[8];
#pragma unroll
  for (int j = 0; j < 8; ++j) colpart[j] = 0.f;

#pragma unroll
  for (int p = 0; p < 4; ++p) {
    int row = rowBase + p * 8 + rgrp;
    const float* X = (row < NHALF) ? (src + (size_t)row * DIM)
                                   : (tgt + (size_t)(row - NHALF) * DIM);
    float4 v0 = *(const float4*)(X + c);
    float4 v1 = *(const float4*)(X + c + 4);
    float vals[8] = {v0.x, v0.y, v0.z, v0.w, v1.x, v1.y, v1.z, v1.w};
    u16x8 h;
    float s = 0.f;
#pragma unroll
    for (int j = 0; j < 8; ++j) {
      unsigned short b = f2bf(vals[j]);
      h[j] = b;
      float rb = bf2f(b);
      s += rb * rb;
      colpart[j] += rb;
    }
    *(u16x8*)(Xb + (size_t)row * DIM + c) = h;
    for (int o = 16; o > 0; o >>= 1) s += __shfl_down(s, o, 32);
    if (lane32 == 0) sq[row] = s;
  }

  __shared__ float cp[8][DIM];
  *(float4*)&cp[rgrp][c]     = make_float4(colpart[0], colpart[1], colpart[2], colpart[3]);
  *(float4*)&cp[rgrp][c + 4] = make_float4(colpart[4], colpart[5], colpart[6], colpart[7]);
  __syncthreads();
  float s8 = 0.f;
#pragma unroll
  for (int r = 0; r < 8; ++r) s8 += cp[r][tid];
  partials[blockIdx.x * DIM + tid] = s8;
}

// ---- Kernel 2: bandwidth reduce, widened (1024 thr, 4-way b-split) ----
// (round-8 exact, verified)
__global__ __launch_bounds__(1024) void mmd_band(
    const float* __restrict__ partials, const float* __restrict__ sq,
    float* __restrict__ c0out) {
  __shared__ float CS[4][DIM];
  __shared__ float L1[1024];
  __shared__ double D2[DIM];
  int tid = threadIdx.x;
  int q = tid >> 8, col = tid & 255;
  float cs = 0.f;
  for (int b = 0; b < PREP_BLOCKS / 4; ++b)
    cs += partials[(q * 64 + b) * DIM + col];
  CS[q][col] = cs;
  const float4* s4 = (const float4*)sq;    // 2048 float4
  float4 va = s4[tid * 2], vb = s4[tid * 2 + 1];
  L1[tid] = (va.x + va.y + va.z + va.w) + (vb.x + vb.y + vb.z + vb.w);
  __syncthreads();
  if (tid < DIM) {
    float ctot = (CS[0][tid] + CS[1][tid]) + (CS[2][tid] + CS[3][tid]);
    D2[tid] = (double)ctot * (double)ctot;
    L1[tid] = (L1[tid] + L1[tid + 256]) + (L1[tid + 512] + L1[tid + 768]);
  }
  __syncthreads();
  for (int o = 128; o > 0; o >>= 1) {
    if (tid < o) { D2[tid] += D2[tid + o]; L1[tid] += L1[tid + o]; }
    __syncthreads();
  }
  if (tid == 0) {
    double S1 = (double)L1[0];
    double S2 = D2[0];
    double sum_l2 = 2.0 * (double)NS * S1 - 2.0 * S2;
    double bw = sum_l2 / ((double)NS * (double)NS - (double)NS);
    bw = bw / 4.0;
    c0out[0] = (float)(1.4426950408889634 / bw);
  }
}

// ---- Kernel 3: 128x128 Gram, dbuf counted-vmcnt (r7) at 4-waves/EU cap ----
// Occupancy model fitted over r0-r9: combined arch+acc VGPRs allocate in
// 64-reg granules from a 512-slot pool/SIMD. All prior rounds sat at
// 76+64=140 -> 192 -> 2 waves/SIMD; VGPR (not LDS) was the residency cap.
// This round: __launch_bounds__(256,4) (cap 128 combined) + sq/c0 preloads
// MOVED AFTER the K-loop (-21 arch regs): in-loop live ~= 64 acc + 32 frag
// + ~15 addr <= 128 -> no spill (r1's spill at this cap needed ~144), and
// with 32-KiB dbuf LDS, residency = min(4 VGPR, 3 LDS) = 3 blocks/CU.
// Spill tripwire: WRITE_SIZE >> 65 KB (r1 signature).
#define STAGE(KT, BUF)                                                        \
  {                                                                           \
    _Pragma("unroll") for (int it = 0; it < 2; ++it) {                        \
      int idx = it * 256 + tid;            /* 0..511, 16B each */             \
      int r = idx >> 2, g = idx & 3;       /* row 0..127, 16B group 0..3 */   \
      int gs = g ^ ((r >> 1) & 3);         /* pre-swizzled SOURCE (rule 21)*/ \
      const unsigned short* ga =                                              \
          Xb + (size_t)(rowBase + r) * DIM + (KT)*BK + gs * 8;                \
      __builtin_amdgcn_global_load_lds(                                       \
          (const __attribute__((address_space(1))) void*)ga,                  \
          (__attribute__((address_space(3))) void*)(&As[BUF][idx * 8]), 16,   \
          0, 0);                                                              \
      const unsigned short* gb =                                              \
          Xb + (size_t)(colBase + r) * DIM + (KT)*BK + gs * 8;                \
      __builtin_amdgcn_global_load_lds(                                       \
          (const __attribute__((address_space(1))) void*)gb,                  \
          (__attribute__((address_space(3))) void*)(&Bs[BUF][idx * 8]), 16,   \
          0, 0);                                                              \
    }                                                                         \
  }

__global__ __launch_bounds__(256, 4) void mmd_gram(
    const unsigned short* __restrict__ Xb, const float* __restrict__ sq,
    const float* __restrict__ c0p, double* __restrict__ accK) {
  int l = blockIdx.x;
  int bj = (int)((sqrtf(8.f * (float)l + 1.f) - 1.f) * 0.5f);
  while ((bj + 1) * (bj + 2) / 2 <= l) bj++;
  while (bj * (bj + 1) / 2 > l) bj--;
  int bi = l - bj * (bj + 1) / 2;

  __shared__ __align__(16) unsigned short As[2][BLK * BK];  // 16 KiB
  __shared__ __align__(16) unsigned short Bs[2][BLK * BK];  // 16 KiB
  int tid = threadIdx.x;
  int wave = tid >> 6;
  int lane = tid & 63;
  int rowBase = bi * BLK, colBase = bj * BLK;
  int wr = (wave >> 1) * 64;   // wave's 64x64 quadrant
  int wc = (wave & 1) * 64;

  f32x4 acc[4][4];
#pragma unroll
  for (int m = 0; m < 4; ++m)
#pragma unroll
    for (int n = 0; n < 4; ++n) acc[m][n] = (f32x4){0.f, 0.f, 0.f, 0.f};

  // pipeline prologue: two K-steps in flight (r7 exact)
  STAGE(0, 0);
  STAGE(1, 1);

#pragma unroll
  for (int kt = 0; kt < NKT; ++kt) {
    int cur = kt & 1;
    // my stage(kt) loads done; stage(kt+1)'s 4 insts may remain in flight
    if (kt == NKT - 1)
      asm volatile("s_waitcnt vmcnt(0)" ::: "memory");
    else
      asm volatile("s_waitcnt vmcnt(4)" ::: "memory");
    __builtin_amdgcn_s_barrier();      // buf[cur] staged by all waves

    bf16x8 af[4], bfr[4];
    int kg = lane >> 4;                // 16B k-group 0..3 of this lane
#pragma unroll
    for (int m = 0; m < 4; ++m) {
      int r = wr + m * 16 + (lane & 15);
      af[m] = *(const bf16x8*)(&As[cur][r * BK + (kg ^ ((r >> 1) & 3)) * 8]);
    }
#pragma unroll
    for (int n = 0; n < 4; ++n) {
      int r = wc + n * 16 + (lane & 15);
      bfr[n] = *(const bf16x8*)(&Bs[cur][r * BK + (kg ^ ((r >> 1) & 3)) * 8]);
    }
    asm volatile("s_waitcnt lgkmcnt(0)" ::: "memory");
    __builtin_amdgcn_sched_barrier(0);   // rule #18: keep MFMA below the wait
    __builtin_amdgcn_s_barrier();        // all waves done reading buf[cur]

    if (kt < NKT - 2) STAGE(kt + 2, cur);  // async overwrite, flies under MFMA

#pragma unroll
    for (int m = 0; m < 4; ++m)
#pragma unroll
      for (int n = 0; n < 4; ++n)
        acc[m][n] = __builtin_amdgcn_mfma_f32_16x16x32_bf16(
            af[m], bfr[n], acc[m][n], 0, 0, 0);
  }

  // ---- epilogue: sq/c0 loads HERE (keeps K-loop register-lean) ----
  float c0v = *c0p;
  float cE = -0.0625f * c0v;     // arg = cE*(sqr+sqc) + t2*acc
  float t2 = -2.f * cE;
  float a_[4][4], b_[4];
  int r4 = (lane >> 4) * 4;
#pragma unroll
  for (int m = 0; m < 4; ++m) {
    f32x4 s4v = *(const f32x4*)&sq[rowBase + wr + m * 16 + r4];
#pragma unroll
    for (int r = 0; r < 4; ++r) a_[m][r] = cE * s4v[r];
  }
#pragma unroll
  for (int n = 0; n < 4; ++n)
    b_[n] = cE * sq[colBase + wc + n * 16 + (lane & 15)];

  float tsum = 0.f;
#pragma unroll
  for (int m = 0; m < 4; ++m)
#pragma unroll
    for (int n = 0; n < 4; ++n)
#pragma unroll
      for (int r = 0; r < 4; ++r) {
        // C/D layout (m89): col = lane&15, row = (lane>>4)*4 + reg
        float arg = fmaf(acc[m][n][r], t2, a_[m][r] + b_[n]);
        float e4 = exp2f(arg);           // e_{k-1} = e_k^2
        float e3 = e4 * e4;
        float e2 = e3 * e3;
        float e1 = e2 * e2;
        float e0 = e1 * e1;
        tsum += ((e4 + e3) + (e2 + e1)) + e0;
      }

  // wave-level shuffle reduce, then tiny cross-wave combine.
  // As is dead after the K-loop (reads drained before the final barrier).
  float* red4 = (float*)&As[0][0];
#pragma unroll
  for (int o = 32; o > 0; o >>= 1) tsum += __shfl_down(tsum, o);
  if (lane == 0) red4[wave] = tsum;
  __syncthreads();
  if (tid == 0) {
    float t = (red4[0] + red4[1]) + (red4[2] + red4[3]);
    float sign = ((bi < HALF_TILES) == (bj < HALF_TILES)) ? 1.f : -1.f;
    float factor = (bi == bj) ? sign : 2.f * sign;  // off-diag tiles doubled
    atomicAdd(accK, (double)(factor * t));
  }
}

// ---- Kernel 4: finalize (round-0 exact) ----
__global__ void mmd_final(const double* __restrict__ accK, float* __restrict__ out) {
  out[0] = (float)(accK[0] / ((double)NHALF * (double)NHALF));
}

extern "C" void kernel_launch(void* const* d_in, const int* in_sizes, int n_in,
                              void* d_out, int out_size, void* d_ws, size_t ws_size,
                              hipStream_t stream) {
  if (ws_size < (size_t)WS_NEED) return;  // need ~4.3 MiB scratch
  const float* src = (const float*)d_in[0];
  const float* tgt = (const float*)d_in[1];
  char* ws = (char*)d_ws;
  unsigned short* Xb = (unsigned short*)(ws + XB_OFF);
  float* sq          = (float*)(ws + SQ_OFF);
  float* partials    = (float*)(ws + PART_OFF);
  double* accK       = (double*)(ws + ACC_OFF);
  float* c0          = (float*)(ws + C0_OFF);

  mmd_prep<<<PREP_BLOCKS, 256, 0, stream>>>(src, tgt, Xb, sq, partials, accK);
  mmd_band<<<1, 1024, 0, stream>>>(partials, sq, c0);
  mmd_gram<<<NTRI, 256, 0, stream>>>(Xb, sq, c0, accK);
  mmd_final<<<1, 1, 0, stream>>>(accK, (float*)d_out);
}

// Round 11
// 58.383 us; speedup vs baseline: 1.0890x; 1.0890x over previous
//
#include <hip/hip_runtime.h>
#include <hip/hip_bf16.h>
#include <stdint.h>

#define NS 8192
#define NHALF 4096
#define DIM 256
#define BLK 128
#define BK 32
#define NKT (DIM / BK)           // 8 K-steps
#define NTILES (NS / BLK)        // 64
#define HALF_TILES (NHALF / BLK) // 32
#define NTRI (NTILES * (NTILES + 1) / 2)  // 2080 upper-tri tiles
#define PREP_BLOCKS 256

typedef __attribute__((ext_vector_type(8))) short bf16x8;
typedef __attribute__((ext_vector_type(4))) float f32x4;
typedef __attribute__((ext_vector_type(2))) float f32x2;
typedef __attribute__((ext_vector_type(8))) unsigned short u16x8;

// workspace layout (bytes) — round-0 proven layout
#define XB_OFF   0                         // bf16 X: 8192*256*2 = 4 MiB
#define SQ_OFF   (NS * DIM * 2)            // f32 sq[8192] = 32 KiB
#define PART_OFF (SQ_OFF + NS * 4)         // f32 partials[256][256] = 256 KiB
#define ACC_OFF  (PART_OFF + PREP_BLOCKS * DIM * 4)  // f64 signed kernel sum
#define C0_OFF   (ACC_OFF + 8)             // f32 log2e / bandwidth
#define WS_NEED  (C0_OFF + 16)

__device__ __forceinline__ unsigned short f2bf(float f) {
  unsigned int u = __float_as_uint(f);
  u += 0x7fffu + ((u >> 16) & 1u);   // round-to-nearest-even
  return (unsigned short)(u >> 16);
}
__device__ __forceinline__ float bf2f(unsigned short h) {
  return __uint_as_float(((unsigned int)h) << 16);
}

// ---- Kernel 1: convert to bf16, row ||x||^2, per-block column partials ----
// (round-0 exact + block 0 zeroes accK, replacing the hipMemsetAsync dispatch)
__global__ __launch_bounds__(256) void mmd_prep(
    const float* __restrict__ src, const float* __restrict__ tgt,
    unsigned short* __restrict__ Xb, float* __restrict__ sq,
    float* __restrict__ partials, double* __restrict__ accK) {
  int tid = threadIdx.x;
  if (blockIdx.x == 0 && tid == 0) accK[0] = 0.0;   // stream-ordered before gram
  int lane32 = tid & 31;
  int rgrp = tid >> 5;
  int c = lane32 * 8;
  int rowBase = blockIdx.x * 32;

  float colpart[8];
#pragma unroll
  for (int j = 0; j < 8; ++j) colpart[j] = 0.f;

#pragma unroll
  for (int p = 0; p < 4; ++p) {
    int row = rowBase + p * 8 + rgrp;
    const float* X = (row < NHALF) ? (src + (size_t)row * DIM)
                                   : (tgt + (size_t)(row - NHALF) * DIM);
    float4 v0 = *(const float4*)(X + c);
    float4 v1 = *(const float4*)(X + c + 4);
    float vals[8] = {v0.x, v0.y, v0.z, v0.w, v1.x, v1.y, v1.z, v1.w};
    u16x8 h;
    float s = 0.f;
#pragma unroll
    for (int j = 0; j < 8; ++j) {
      unsigned short b = f2bf(vals[j]);
      h[j] = b;
      float rb = bf2f(b);
      s += rb * rb;
      colpart[j] += rb;
    }
    *(u16x8*)(Xb + (size_t)row * DIM + c) = h;
    for (int o = 16; o > 0; o >>= 1) s += __shfl_down(s, o, 32);
    if (lane32 == 0) sq[row] = s;
  }

  __shared__ float cp[8][DIM];
  *(float4*)&cp[rgrp][c]     = make_float4(colpart[0], colpart[1], colpart[2], colpart[3]);
  *(float4*)&cp[rgrp][c + 4] = make_float4(colpart[4], colpart[5], colpart[6], colpart[7]);
  __syncthreads();
  float s8 = 0.f;
#pragma unroll
  for (int r = 0; r < 8; ++r) s8 += cp[r][tid];
  partials[blockIdx.x * DIM + tid] = s8;
}

// ---- Kernel 2: bandwidth reduce, widened (1024 thr, 4-way b-split) ----
// (round-8 exact, verified)
__global__ __launch_bounds__(1024) void mmd_band(
    const float* __restrict__ partials, const float* __restrict__ sq,
    float* __restrict__ c0out) {
  __shared__ float CS[4][DIM];
  __shared__ float L1[1024];
  __shared__ double D2[DIM];
  int tid = threadIdx.x;
  int q = tid >> 8, col = tid & 255;
  float cs = 0.f;
  for (int b = 0; b < PREP_BLOCKS / 4; ++b)
    cs += partials[(q * 64 + b) * DIM + col];
  CS[q][col] = cs;
  const float4* s4 = (const float4*)sq;    // 2048 float4
  float4 va = s4[tid * 2], vb = s4[tid * 2 + 1];
  L1[tid] = (va.x + va.y + va.z + va.w) + (vb.x + vb.y + vb.z + vb.w);
  __syncthreads();
  if (tid < DIM) {
    float ctot = (CS[0][tid] + CS[1][tid]) + (CS[2][tid] + CS[3][tid]);
    D2[tid] = (double)ctot * (double)ctot;
    L1[tid] = (L1[tid] + L1[tid + 256]) + (L1[tid + 512] + L1[tid + 768]);
  }
  __syncthreads();
  for (int o = 128; o > 0; o >>= 1) {
    if (tid < o) { D2[tid] += D2[tid + o]; L1[tid] += L1[tid + o]; }
    __syncthreads();
  }
  if (tid == 0) {
    double S1 = (double)L1[0];
    double S2 = D2[0];
    double sum_l2 = 2.0 * (double)NS * S1 - 2.0 * S2;
    double bw = sum_l2 / ((double)NS * (double)NS - (double)NS);
    bw = bw / 4.0;
    c0out[0] = (float)(1.4426950408889634 / bw);
  }
}

// ---- Kernel 3: 128x128 Gram, TRIPLE-buffered counted-vmcnt pipeline ----
// (round-9 exact — best gram structure: 46.6 µs) + PACKED-f32 epilogue.
// r0-r10 conclusion: busy inventory invariant (MFMA ~6.6 µs, VALU ~18 µs)
// across all scheduling/occupancy variants; remaining lever = VALU inventory.
// Epilogue pairs over the acc reg index so mul/add/fma lower to VOP3P
// v_pk_{fma,mul,add}_f32 (gfx90a+); exp2 stays scalar. ~11 -> ~5 ops/elem.
// Same pairwise arithmetic as rounds 1-2: absmax 0.0 both times, and r2's
// counters showed -25% VALU-busy vs the scalar epilogue.
#define STAGE(KT, BUF)                                                        \
  {                                                                           \
    _Pragma("unroll") for (int it = 0; it < 2; ++it) {                        \
      int idx = it * 256 + tid;            /* 0..511, 16B each */             \
      int r = idx >> 2, g = idx & 3;       /* row 0..127, 16B group 0..3 */   \
      int gs = g ^ ((r >> 1) & 3);         /* pre-swizzled SOURCE (rule 21)*/ \
      const unsigned short* ga =                                              \
          Xb + (size_t)(rowBase + r) * DIM + (KT)*BK + gs * 8;                \
      __builtin_amdgcn_global_load_lds(                                       \
          (const __attribute__((address_space(1))) void*)ga,                  \
          (__attribute__((address_space(3))) void*)(&As[BUF][idx * 8]), 16,   \
          0, 0);                                                              \
      const unsigned short* gb =                                              \
          Xb + (size_t)(colBase + r) * DIM + (KT)*BK + gs * 8;                \
      __builtin_amdgcn_global_load_lds(                                       \
          (const __attribute__((address_space(1))) void*)gb,                  \
          (__attribute__((address_space(3))) void*)(&Bs[BUF][idx * 8]), 16,   \
          0, 0);                                                              \
    }                                                                         \
  }

__global__ __launch_bounds__(256, 2) void mmd_gram(
    const unsigned short* __restrict__ Xb, const float* __restrict__ sq,
    const float* __restrict__ c0p, double* __restrict__ accK) {
  int l = blockIdx.x;
  int bj = (int)((sqrtf(8.f * (float)l + 1.f) - 1.f) * 0.5f);
  while ((bj + 1) * (bj + 2) / 2 <= l) bj++;
  while (bj * (bj + 1) / 2 > l) bj--;
  int bi = l - bj * (bj + 1) / 2;

  __shared__ __align__(16) unsigned short As[3][BLK * BK];  // 24 KiB
  __shared__ __align__(16) unsigned short Bs[3][BLK * BK];  // 24 KiB
  int tid = threadIdx.x;
  int wave = tid >> 6;
  int lane = tid & 63;
  int rowBase = bi * BLK, colBase = bj * BLK;
  int wr = (wave >> 1) * 64;   // wave's 64x64 quadrant
  int wc = (wave & 1) * 64;

  // prologue loads: issue now, USED only in the epilogue (no early wait);
  // kt0's vmcnt(4) drains them together with stage(0).
  float c0v = *c0p;
  float sqr[4][4], sqc[4];
  int r4 = (lane >> 4) * 4;
#pragma unroll
  for (int m = 0; m < 4; ++m)
#pragma unroll
    for (int r = 0; r < 4; ++r)
      sqr[m][r] = sq[rowBase + wr + m * 16 + r4 + r];
#pragma unroll
  for (int n = 0; n < 4; ++n)
    sqc[n] = sq[colBase + wc + n * 16 + (lane & 15)];

  f32x4 acc[4][4];
#pragma unroll
  for (int m = 0; m < 4; ++m)
#pragma unroll
    for (int n = 0; n < 4; ++n) acc[m][n] = (f32x4){0.f, 0.f, 0.f, 0.f};

  // pipeline prologue: two K-steps in flight
  STAGE(0, 0);
  STAGE(1, 1);

#pragma unroll
  for (int kt = 0; kt < NKT; ++kt) {
    int cur = kt % 3;
    // my stage(kt) loads done; stage(kt+1)'s 4 insts may remain in flight
    if (kt == NKT - 1)
      asm volatile("s_waitcnt vmcnt(0)" ::: "memory");
    else
      asm volatile("s_waitcnt vmcnt(4)" ::: "memory");
    __builtin_amdgcn_s_barrier();      // buf[cur] staged by all waves

    bf16x8 af[4], bfr[4];
    int kg = lane >> 4;                // 16B k-group 0..3 of this lane
#pragma unroll
    for (int m = 0; m < 4; ++m) {
      int r = wr + m * 16 + (lane & 15);
      af[m] = *(const bf16x8*)(&As[cur][r * BK + (kg ^ ((r >> 1) & 3)) * 8]);
    }
#pragma unroll
    for (int n = 0; n < 4; ++n) {
      int r = wc + n * 16 + (lane & 15);
      bfr[n] = *(const bf16x8*)(&Bs[cur][r * BK + (kg ^ ((r >> 1) & 3)) * 8]);
    }
    asm volatile("s_waitcnt lgkmcnt(0)" ::: "memory");
    __builtin_amdgcn_sched_barrier(0);   // rule #18: keep MFMA below the wait

    // overwrite buf[(kt+2)%3] == buf[(kt-1)%3]: all its readers drained
    // before barrier(kt) -> no second barrier needed (triple buffer).
    if (kt < NKT - 2) STAGE(kt + 2, (kt + 2) % 3);

#pragma unroll
    for (int m = 0; m < 4; ++m)
#pragma unroll
      for (int n = 0; n < 4; ++n)
        acc[m][n] = __builtin_amdgcn_mfma_f32_16x16x32_bf16(
            af[m], bfr[n], acc[m][n], 0, 0, 0);
  }

  // ---- epilogue: l2 -> sum of 5 Gaussians, PACKED f32 pairs ----
  // Per pair: pk_add(a+b), pk_fma(arg), 2x v_exp, 4x pk_mul, 4x pk_add.
  float cE = -0.0625f * c0v;     // arg = cE*(sqr+sqc) + t2*acc
  float t2 = -2.f * cE;
  f32x2 t2v = (f32x2){t2, t2};
  f32x2 aP[4][2];
#pragma unroll
  for (int m = 0; m < 4; ++m)
#pragma unroll
    for (int p = 0; p < 2; ++p)
      aP[m][p] = (f32x2){cE * sqr[m][p * 2], cE * sqr[m][p * 2 + 1]};
  f32x2 ts = (f32x2){0.f, 0.f};
#pragma unroll
  for (int m = 0; m < 4; ++m)
#pragma unroll
    for (int n = 0; n < 4; ++n) {
      f32x2 bv = (f32x2){cE * sqc[n], cE * sqc[n]};
#pragma unroll
      for (int p = 0; p < 2; ++p) {
        // C/D layout (m89): col = lane&15, row = (lane>>4)*4 + reg
        f32x2 a2 = (f32x2){acc[m][n][p * 2], acc[m][n][p * 2 + 1]};
        f32x2 arg = a2 * t2v + (aP[m][p] + bv);   // contracts to v_pk_fma_f32
        f32x2 e4;
        e4.x = exp2f(arg.x);
        e4.y = exp2f(arg.y);
        f32x2 e3 = e4 * e4;            // v_pk_mul_f32 chain
        f32x2 e2 = e3 * e3;
        f32x2 e1 = e2 * e2;
        f32x2 e0 = e1 * e1;
        ts += ((e4 + e3) + (e2 + e1)) + e0;
      }
    }
  float tsum = ts.x + ts.y;

  // wave-level shuffle reduce, then tiny cross-wave combine.
  // As[0] (buf 0) last read at kt=6; all waves passed barrier(7) -> safe.
  float* red4 = (float*)&As[0][0];
#pragma unroll
  for (int o = 32; o > 0; o >>= 1) tsum += __shfl_down(tsum, o);
  if (lane == 0) red4[wave] = tsum;
  __syncthreads();
  if (tid == 0) {
    float t = (red4[0] + red4[1]) + (red4[2] + red4[3]);
    float sign = ((bi < HALF_TILES) == (bj < HALF_TILES)) ? 1.f : -1.f;
    float factor = (bi == bj) ? sign : 2.f * sign;  // off-diag tiles doubled
    atomicAdd(accK, (double)(factor * t));
  }
}

// ---- Kernel 4: finalize (round-0 exact) ----
__global__ void mmd_final(const double* __restrict__ accK, float* __restrict__ out) {
  out[0] = (float)(accK[0] / ((double)NHALF * (double)NHALF));
}

extern "C" void kernel_launch(void* const* d_in, const int* in_sizes, int n_in,
                              void* d_out, int out_size, void* d_ws, size_t ws_size,
                              hipStream_t stream) {
  if (ws_size < (size_t)WS_NEED) return;  // need ~4.3 MiB scratch
  const float* src = (const float*)d_in[0];
  const float* tgt = (const float*)d_in[1];
  char* ws = (char*)d_ws;
  unsigned short* Xb = (unsigned short*)(ws + XB_OFF);
  float* sq          = (float*)(ws + SQ_OFF);
  float* partials    = (float*)(ws + PART_OFF);
  double* accK       = (double*)(ws + ACC_OFF);
  float* c0          = (float*)(ws + C0_OFF);

  mmd_prep<<<PREP_BLOCKS, 256, 0, stream>>>(src, tgt, Xb, sq, partials, accK);
  mmd_band<<<1, 1024, 0, stream>>>(partials, sq, c0);
  mmd_gram<<<NTRI, 256, 0, stream>>>(Xb, sq, c0, accK);
  mmd_final<<<1, 1, 0, stream>>>(accK, (float*)d_out);
}

// Round 12
// 56.336 us; speedup vs baseline: 1.1286x; 1.0363x over previous
//
#include <hip/hip_runtime.h>
#include <hip/hip_bf16.h>
#include <stdint.h>

#define NS 8192
#define NHALF 4096
#define DIM 256
#define BLK 128
#define BK 32
#define NKT (DIM / BK)           // 8 K-steps
#define NTILES (NS / BLK)        // 64
#define HALF_TILES (NHALF / BLK) // 32
#define NTRI (NTILES * (NTILES + 1) / 2)  // 2080 upper-tri tiles
#define PREP_BLOCKS 256

typedef __attribute__((ext_vector_type(8))) short bf16x8;
typedef __attribute__((ext_vector_type(4))) float f32x4;
typedef __attribute__((ext_vector_type(2))) float f32x2;
typedef __attribute__((ext_vector_type(8))) unsigned short u16x8;

// workspace layout (bytes) — round-0 proven layout
#define XB_OFF   0                         // bf16 X: 8192*256*2 = 4 MiB
#define SQ_OFF   (NS * DIM * 2)            // f32 sq[8192] = 32 KiB
#define PART_OFF (SQ_OFF + NS * 4)         // f32 partials[256][256] = 256 KiB
#define ACC_OFF  (PART_OFF + PREP_BLOCKS * DIM * 4)  // f64 signed kernel sum
#define C0_OFF   (ACC_OFF + 8)             // f32 log2e / bandwidth
#define WS_NEED  (C0_OFF + 16)

__device__ __forceinline__ unsigned short f2bf(float f) {
  unsigned int u = __float_as_uint(f);
  u += 0x7fffu + ((u >> 16) & 1u);   // round-to-nearest-even
  return (unsigned short)(u >> 16);
}
__device__ __forceinline__ float bf2f(unsigned short h) {
  return __uint_as_float(((unsigned int)h) << 16);
}

// bare v_exp_f32 — exp2f() routes through OCML (range/denorm fixup ops);
// args here are <= 0, flush-to-zero tail is numerically irrelevant.
__device__ __forceinline__ float fast_exp2(float x) {
#if __has_builtin(__builtin_amdgcn_exp2f)
  return __builtin_amdgcn_exp2f(x);
#else
  return exp2f(x);
#endif
}

// ---- Kernel 1: convert to bf16, row ||x||^2, per-block column partials ----
// (round-0 exact + block 0 zeroes accK, replacing the hipMemsetAsync dispatch)
__global__ __launch_bounds__(256) void mmd_prep(
    const float* __restrict__ src, const float* __restrict__ tgt,
    unsigned short* __restrict__ Xb, float* __restrict__ sq,
    float* __restrict__ partials, double* __restrict__ accK) {
  int tid = threadIdx.x;
  if (blockIdx.x == 0 && tid == 0) accK[0] = 0.0;   // stream-ordered before gram
  int lane32 = tid & 31;
  int rgrp = tid >> 5;
  int c = lane32 * 8;
  int rowBase = blockIdx.x * 32;

  float colpart[8];
#pragma unroll
  for (int j = 0; j < 8; ++j) colpart[j] = 0.f;

#pragma unroll
  for (int p = 0; p < 4; ++p) {
    int row = rowBase + p * 8 + rgrp;
    const float* X = (row < NHALF) ? (src + (size_t)row * DIM)
                                   : (tgt + (size_t)(row - NHALF) * DIM);
    float4 v0 = *(const float4*)(X + c);
    float4 v1 = *(const float4*)(X + c + 4);
    float vals[8] = {v0.x, v0.y, v0.z, v0.w, v1.x, v1.y, v1.z, v1.w};
    u16x8 h;
    float s = 0.f;
#pragma unroll
    for (int j = 0; j < 8; ++j) {
      unsigned short b = f2bf(vals[j]);
      h[j] = b;
      float rb = bf2f(b);
      s += rb * rb;
      colpart[j] += rb;
    }
    *(u16x8*)(Xb + (size_t)row * DIM + c) = h;
    for (int o = 16; o > 0; o >>= 1) s += __shfl_down(s, o, 32);
    if (lane32 == 0) sq[row] = s;
  }

  __shared__ float cp[8][DIM];
  *(float4*)&cp[rgrp][c]     = make_float4(colpart[0], colpart[1], colpart[2], colpart[3]);
  *(float4*)&cp[rgrp][c + 4] = make_float4(colpart[4], colpart[5], colpart[6], colpart[7]);
  __syncthreads();
  float s8 = 0.f;
#pragma unroll
  for (int r = 0; r < 8; ++r) s8 += cp[r][tid];
  partials[blockIdx.x * DIM + tid] = s8;
}

// ---- Kernel 2: bandwidth reduce, widened (1024 thr, 4-way b-split) ----
// (round-8 exact, verified)
__global__ __launch_bounds__(1024) void mmd_band(
    const float* __restrict__ partials, const float* __restrict__ sq,
    float* __restrict__ c0out) {
  __shared__ float CS[4][DIM];
  __shared__ float L1[1024];
  __shared__ double D2[DIM];
  int tid = threadIdx.x;
  int q = tid >> 8, col = tid & 255;
  float cs = 0.f;
  for (int b = 0; b < PREP_BLOCKS / 4; ++b)
    cs += partials[(q * 64 + b) * DIM + col];
  CS[q][col] = cs;
  const float4* s4 = (const float4*)sq;    // 2048 float4
  float4 va = s4[tid * 2], vb = s4[tid * 2 + 1];
  L1[tid] = (va.x + va.y + va.z + va.w) + (vb.x + vb.y + vb.z + vb.w);
  __syncthreads();
  if (tid < DIM) {
    float ctot = (CS[0][tid] + CS[1][tid]) + (CS[2][tid] + CS[3][tid]);
    D2[tid] = (double)ctot * (double)ctot;
    L1[tid] = (L1[tid] + L1[tid + 256]) + (L1[tid + 512] + L1[tid + 768]);
  }
  __syncthreads();
  for (int o = 128; o > 0; o >>= 1) {
    if (tid < o) { D2[tid] += D2[tid + o]; L1[tid] += L1[tid + o]; }
    __syncthreads();
  }
  if (tid == 0) {
    double S1 = (double)L1[0];
    double S2 = D2[0];
    double sum_l2 = 2.0 * (double)NS * S1 - 2.0 * S2;
    double bw = sum_l2 / ((double)NS * (double)NS - (double)NS);
    bw = bw / 4.0;
    c0out[0] = (float)(1.4426950408889634 / bw);
  }
}

// ---- Kernel 3: 128x128 Gram, TRIPLE-buffered counted-vmcnt pipeline ----
// (round-9/11 structure) + two instruction-level changes:
// (1) NO forced lgkmcnt(0) before the MFMA cluster: ds_reads are plain C++
//     loads (compiler-visible), so the compiler emits fine-grained
//     lgkmcnt(4/3/1/0) interleaving ds_read latency with the first MFMAs
//     (m97 pattern). r11's hard join serialized read-latency + MFMA.
//     sched_barrier(0) directly after s_barrier pins reads below the
//     barrier; next iteration's vmcnt asm ("memory") bounds sinking.
// (2) raw v_exp_f32 epilogue (fast_exp2).
#define STAGE(KT, BUF)                                                        \
  {                                                                           \
    _Pragma("unroll") for (int it = 0; it < 2; ++it) {                        \
      int idx = it * 256 + tid;            /* 0..511, 16B each */             \
      int r = idx >> 2, g = idx & 3;       /* row 0..127, 16B group 0..3 */   \
      int gs = g ^ ((r >> 1) & 3);         /* pre-swizzled SOURCE (rule 21)*/ \
      const unsigned short* ga =                                              \
          Xb + (size_t)(rowBase + r) * DIM + (KT)*BK + gs * 8;                \
      __builtin_amdgcn_global_load_lds(                                       \
          (const __attribute__((address_space(1))) void*)ga,                  \
          (__attribute__((address_space(3))) void*)(&As[BUF][idx * 8]), 16,   \
          0, 0);                                                              \
      const unsigned short* gb =                                              \
          Xb + (size_t)(colBase + r) * DIM + (KT)*BK + gs * 8;                \
      __builtin_amdgcn_global_load_lds(                                       \
          (const __attribute__((address_space(1))) void*)gb,                  \
          (__attribute__((address_space(3))) void*)(&Bs[BUF][idx * 8]), 16,   \
          0, 0);                                                              \
    }                                                                         \
  }

__global__ __launch_bounds__(256, 2) void mmd_gram(
    const unsigned short* __restrict__ Xb, const float* __restrict__ sq,
    const float* __restrict__ c0p, double* __restrict__ accK) {
  int l = blockIdx.x;
  int bj = (int)((sqrtf(8.f * (float)l + 1.f) - 1.f) * 0.5f);
  while ((bj + 1) * (bj + 2) / 2 <= l) bj++;
  while (bj * (bj + 1) / 2 > l) bj--;
  int bi = l - bj * (bj + 1) / 2;

  __shared__ __align__(16) unsigned short As[3][BLK * BK];  // 24 KiB
  __shared__ __align__(16) unsigned short Bs[3][BLK * BK];  // 24 KiB
  int tid = threadIdx.x;
  int wave = tid >> 6;
  int lane = tid & 63;
  int rowBase = bi * BLK, colBase = bj * BLK;
  int wr = (wave >> 1) * 64;   // wave's 64x64 quadrant
  int wc = (wave & 1) * 64;

  // prologue loads: issue now, USED only in the epilogue (no early wait);
  // kt0's vmcnt(4) drains them together with stage(0). 9 VMEM insts total.
  float c0v = *c0p;
  int r4 = (lane >> 4) * 4;
  f32x4 sqr4[4];
#pragma unroll
  for (int m = 0; m < 4; ++m)
    sqr4[m] = *(const f32x4*)&sq[rowBase + wr + m * 16 + r4];
  float sqc[4];
#pragma unroll
  for (int n = 0; n < 4; ++n)
    sqc[n] = sq[colBase + wc + n * 16 + (lane & 15)];

  f32x4 acc[4][4];
#pragma unroll
  for (int m = 0; m < 4; ++m)
#pragma unroll
    for (int n = 0; n < 4; ++n) acc[m][n] = (f32x4){0.f, 0.f, 0.f, 0.f};

  // pipeline prologue: two K-steps in flight
  STAGE(0, 0);
  STAGE(1, 1);

#pragma unroll
  for (int kt = 0; kt < NKT; ++kt) {
    int cur = kt % 3;
    // my stage(kt) loads done; stage(kt+1)'s 4 insts may remain in flight
    if (kt == NKT - 1)
      asm volatile("s_waitcnt vmcnt(0)" ::: "memory");
    else
      asm volatile("s_waitcnt vmcnt(4)" ::: "memory");
    __builtin_amdgcn_s_barrier();        // buf[cur] staged by all waves
    __builtin_amdgcn_sched_barrier(0);   // pin ds_reads below the barrier

    bf16x8 af[4], bfr[4];
    int kg = lane >> 4;                // 16B k-group 0..3 of this lane
#pragma unroll
    for (int m = 0; m < 4; ++m) {
      int r = wr + m * 16 + (lane & 15);
      af[m] = *(const bf16x8*)(&As[cur][r * BK + (kg ^ ((r >> 1) & 3)) * 8]);
    }
#pragma unroll
    for (int n = 0; n < 4; ++n) {
      int r = wc + n * 16 + (lane & 15);
      bfr[n] = *(const bf16x8*)(&Bs[cur][r * BK + (kg ^ ((r >> 1) & 3)) * 8]);
    }

    // overwrite buf[(kt+2)%3] == buf[(kt-1)%3]: all its readers drained
    // before barrier(kt) -> no second barrier needed (triple buffer).
    if (kt < NKT - 2) STAGE(kt + 2, (kt + 2) % 3);

    // compiler inserts fine-grained lgkmcnt before each MFMA use.
#pragma unroll
    for (int m = 0; m < 4; ++m)
#pragma unroll
      for (int n = 0; n < 4; ++n)
        acc[m][n] = __builtin_amdgcn_mfma_f32_16x16x32_bf16(
            af[m], bfr[n], acc[m][n], 0, 0, 0);
  }

  // ---- epilogue: l2 -> sum of 5 Gaussians, PACKED f32 pairs + raw exp ----
  float cE = -0.0625f * c0v;     // arg = cE*(sqr+sqc) + t2*acc
  float t2 = -2.f * cE;
  f32x2 t2v = (f32x2){t2, t2};
  f32x2 aP[4][2];
#pragma unroll
  for (int m = 0; m < 4; ++m)
#pragma unroll
    for (int p = 0; p < 2; ++p)
      aP[m][p] = (f32x2){cE * sqr4[m][p * 2], cE * sqr4[m][p * 2 + 1]};
  f32x2 ts = (f32x2){0.f, 0.f};
#pragma unroll
  for (int m = 0; m < 4; ++m)
#pragma unroll
    for (int n = 0; n < 4; ++n) {
      f32x2 bv = (f32x2){cE * sqc[n], cE * sqc[n]};
#pragma unroll
      for (int p = 0; p < 2; ++p) {
        // C/D layout (m89): col = lane&15, row = (lane>>4)*4 + reg
        f32x2 a2 = (f32x2){acc[m][n][p * 2], acc[m][n][p * 2 + 1]};
        f32x2 arg = a2 * t2v + (aP[m][p] + bv);   // contracts to v_pk_fma_f32
        f32x2 e4;
        e4.x = fast_exp2(arg.x);       // bare v_exp_f32
        e4.y = fast_exp2(arg.y);
        f32x2 e3 = e4 * e4;            // v_pk_mul_f32 chain
        f32x2 e2 = e3 * e3;
        f32x2 e1 = e2 * e2;
        f32x2 e0 = e1 * e1;
        ts += ((e4 + e3) + (e2 + e1)) + e0;
      }
    }
  float tsum = ts.x + ts.y;

  // wave-level shuffle reduce, then tiny cross-wave combine.
  // As[0] (buf 0) last read at kt=6; all waves passed barrier(7) -> safe.
  float* red4 = (float*)&As[0][0];
#pragma unroll
  for (int o = 32; o > 0; o >>= 1) tsum += __shfl_down(tsum, o);
  if (lane == 0) red4[wave] = tsum;
  __syncthreads();
  if (tid == 0) {
    float t = (red4[0] + red4[1]) + (red4[2] + red4[3]);
    float sign = ((bi < HALF_TILES) == (bj < HALF_TILES)) ? 1.f : -1.f;
    float factor = (bi == bj) ? sign : 2.f * sign;  // off-diag tiles doubled
    atomicAdd(accK, (double)(factor * t));
  }
}

// ---- Kernel 4: finalize (round-0 exact) ----
__global__ void mmd_final(const double* __restrict__ accK, float* __restrict__ out) {
  out[0] = (float)(accK[0] / ((double)NHALF * (double)NHALF));
}

extern "C" void kernel_launch(void* const* d_in, const int* in_sizes, int n_in,
                              void* d_out, int out_size, void* d_ws, size_t ws_size,
                              hipStream_t stream) {
  if (ws_size < (size_t)WS_NEED) return;  // need ~4.3 MiB scratch
  const float* src = (const float*)d_in[0];
  const float* tgt = (const float*)d_in[1];
  char* ws = (char*)d_ws;
  unsigned short* Xb = (unsigned short*)(ws + XB_OFF);
  float* sq          = (float*)(ws + SQ_OFF);
  float* partials    = (float*)(ws + PART_OFF);
  double* accK       = (double*)(ws + ACC_OFF);
  float* c0          = (float*)(ws + C0_OFF);

  mmd_prep<<<PREP_BLOCKS, 256, 0, stream>>>(src, tgt, Xb, sq, partials, accK);
  mmd_band<<<1, 1024, 0, stream>>>(partials, sq, c0);
  mmd_gram<<<NTRI, 256, 0, stream>>>(Xb, sq, c0, accK);
  mmd_final<<<1, 1, 0, stream>>>(accK, (float*)d_out);
}